// Round 7
// baseline (158.112 us; speedup 1.0000x reference)
//
#include <hip/hip_runtime.h>
#include <hip/hip_bf16.h>

typedef __bf16 bf16x8 __attribute__((ext_vector_type(8)));
typedef float f32x4 __attribute__((ext_vector_type(4)));

#define N_NODES 50000
#define NEDGE 160000
#define NSLOT (2 * N_NODES)
#define CS 50176            // 49 * 1024, padded per-rel stride
#define BLKS_PER_REL 49
#define HSZ ((size_t)N_NODES * 128)

// ---- workspace layout (bytes) ----
constexpr size_t OFF_WFRAG = 0;                                    // 2 basis frag sets, 65536 B
constexpr size_t OFF_XB    = 65536;                                // 100k x 128 bf16 = 25.6 MB
constexpr size_t OFF_Y     = OFF_XB + 25600000;                    // 100k x 256 bf16 = 51.2 MB
constexpr size_t OFF_CNT   = OFF_Y + 51200000;                     // 4*CS*4
constexpr size_t OFF_IPTR  = OFF_CNT + (size_t)4 * CS * 4;
constexpr size_t OFF_CUR   = OFF_IPTR + (size_t)4 * CS * 4;
constexpr size_t OFF_PART  = OFF_CUR + (size_t)4 * CS * 4;         // 196*4, pad 1024
constexpr size_t OFF_SRC   = OFF_PART + 1024;                      // 4*E*2 = 1.28 MB (uint16)

// Basis fragments: offset = (((b*8+n)*4+kk)*64+lane)*8 + j
// element = weight[b][k][o], k = kk*32 + (lane>>4)*8 + j, o = n*16 + (lane&15)
__global__ __launch_bounds__(256) void wfrag_kernel(const float* __restrict__ weight,
                                                    __bf16* __restrict__ wfrag) {
    int tid = blockIdx.x * 256 + threadIdx.x;  // 32768 total
    int j    = tid & 7;
    int lane = (tid >> 3) & 63;
    int kk   = (tid >> 9) & 3;
    int n    = (tid >> 11) & 7;
    int b    = tid >> 14;
    int k = kk * 32 + ((lane >> 4) << 3) + j;
    int o = (n << 4) + (lane & 15);
    wfrag[tid] = (__bf16)weight[b * 16384 + k * 128 + o];
}

// xb[type*N + row] = bf16(x_type[row]), 8 floats -> 8 bf16 per thread
__global__ __launch_bounds__(256) void cast_kernel(const float* __restrict__ x0,
                                                   const float* __restrict__ x1,
                                                   __bf16* __restrict__ xb) {
    int ty = blockIdx.y;
    const float* x = ty ? x1 : x0;
    __bf16* o = xb + (size_t)ty * HSZ;
    int i = blockIdx.x * 256 + threadIdx.x;
    float4 f0 = reinterpret_cast<const float4*>(x)[2 * i];
    float4 f1 = reinterpret_cast<const float4*>(x)[2 * i + 1];
    union { __bf16 b[8]; uint4 v; } pk;
    pk.b[0] = (__bf16)f0.x; pk.b[1] = (__bf16)f0.y;
    pk.b[2] = (__bf16)f0.z; pk.b[3] = (__bf16)f0.w;
    pk.b[4] = (__bf16)f1.x; pk.b[5] = (__bf16)f1.y;
    pk.b[6] = (__bf16)f1.z; pk.b[7] = (__bf16)f1.w;
    reinterpret_cast<uint4*>(o)[i] = pk.v;
}

// Thread tid handles edge tid of ALL 4 relations: 4 independent atomic chains.
__global__ __launch_bounds__(256) void hist4_kernel(const int* __restrict__ d0,
                                                    const int* __restrict__ d1,
                                                    const int* __restrict__ d2,
                                                    const int* __restrict__ d3,
                                                    int* __restrict__ counts) {
    int tid = blockIdx.x * 256 + threadIdx.x;
    if (tid >= NEDGE) return;
    int v0 = d0[tid], v1 = d1[tid], v2 = d2[tid], v3 = d3[tid];
    atomicAdd(&counts[0 * CS + v0], 1);
    atomicAdd(&counts[1 * CS + v1], 1);
    atomicAdd(&counts[2 * CS + v2], 1);
    atomicAdd(&counts[3 * CS + v3], 1);
}

// Per-block partial sums: 49 blocks/rel, 1024 counts/block (int4 per thread).
__global__ __launch_bounds__(256) void block_sums_kernel(const int* __restrict__ counts,
                                                         int* __restrict__ partials) {
    int rel = blockIdx.x / BLKS_PER_REL;
    int blk = blockIdx.x - rel * BLKS_PER_REL;
    const int4* base = reinterpret_cast<const int4*>(counts + rel * CS) + blk * 256;
    int4 v = base[threadIdx.x];
    int s = v.x + v.y + v.z + v.w;
#pragma unroll
    for (int d = 1; d < 64; d <<= 1) s += __shfl_xor(s, d, 64);
    __shared__ int wsum[4];
    int wave = threadIdx.x >> 6;
    int lane = threadIdx.x & 63;
    if (lane == 0) wsum[wave] = s;
    __syncthreads();
    if (threadIdx.x == 0)
        partials[blockIdx.x] = wsum[0] + wsum[1] + wsum[2] + wsum[3];
}

// Exclusive scan + write indptr and cursor (int4 stores).
__global__ __launch_bounds__(256) void scan_write_kernel(const int* __restrict__ counts,
                                                         const int* __restrict__ partials,
                                                         int* __restrict__ indptr,
                                                         int* __restrict__ cursor) {
    int rel = blockIdx.x / BLKS_PER_REL;
    int blk = blockIdx.x - rel * BLKS_PER_REL;
    int lane = threadIdx.x & 63;
    int wave = threadIdx.x >> 6;

    int pv = (lane < blk) ? partials[rel * BLKS_PER_REL + lane] : 0;
#pragma unroll
    for (int d = 1; d < 64; d <<= 1) pv += __shfl_xor(pv, d, 64);

    const int4* base = reinterpret_cast<const int4*>(counts + rel * CS) + blk * 256;
    int4 v = base[threadIdx.x];
    int ts = v.x + v.y + v.z + v.w;

    int s = ts;
#pragma unroll
    for (int d = 1; d < 64; d <<= 1) {
        int n = __shfl_up(s, d, 64);
        if (lane >= d) s += n;
    }
    int exclw = s - ts;

    __shared__ int wtot[4];
    if (lane == 63) wtot[wave] = s;
    __syncthreads();
    int woff = 0;
    if (wave > 0) woff += wtot[0];
    if (wave > 1) woff += wtot[1];
    if (wave > 2) woff += wtot[2];

    int e0 = pv + woff + exclw;
    int4 ip;
    ip.x = e0;
    ip.y = e0 + v.x;
    ip.z = ip.y + v.y;
    ip.w = ip.z + v.z;
    reinterpret_cast<int4*>(indptr + rel * CS)[blk * 256 + threadIdx.x] = ip;
    reinterpret_cast<int4*>(cursor + rel * CS)[blk * 256 + threadIdx.x] = ip;
}

// srcids16[rel][pos] = (uint16)src, pos = cursor[rel][dst]++. 4 chains/thread.
__global__ __launch_bounds__(256) void fill4_kernel(const int* __restrict__ s0, const int* __restrict__ d0,
                                                    const int* __restrict__ s1, const int* __restrict__ d1,
                                                    const int* __restrict__ s2, const int* __restrict__ d2,
                                                    const int* __restrict__ s3, const int* __restrict__ d3,
                                                    int* __restrict__ cursor,
                                                    unsigned short* __restrict__ srcids) {
    int tid = blockIdx.x * 256 + threadIdx.x;
    if (tid >= NEDGE) return;
    int dd[4] = {d0[tid], d1[tid], d2[tid], d3[tid]};
    int ss[4] = {s0[tid], s1[tid], s2[tid], s3[tid]};
#pragma unroll
    for (int r = 0; r < 4; ++r) {
        int pos = atomicAdd(&cursor[r * CS + dd[r]], 1);
        __builtin_nontemporal_store((unsigned short)ss[r],
                                    &srcids[(size_t)r * NEDGE + pos]);
    }
}

// One wave per dst slot. Unweighted per-relation sums (2 adds/edge/lane),
// w_comp coefficients applied once per slot at the end.
__global__ __launch_bounds__(256) void aggregate_y_kernel(const __bf16* __restrict__ xb,
                                                          const int* __restrict__ indptr,
                                                          const unsigned short* __restrict__ srcids,
                                                          const float* __restrict__ wcomp,
                                                          __bf16* __restrict__ y) {
    int idx = blockIdx.x * 256 + threadIdx.x;
    int slot = idx >> 6;
    int lane = idx & 63;
    int p = slot >= N_NODES;
    int node = slot - p * N_NODES;
    int rA = p, rB = p + 2;

    int begA = indptr[rA * CS + node];
    int dA   = indptr[rA * CS + node + 1] - begA;
    int begB = indptr[rB * CS + node];
    int dB   = indptr[rB * CS + node + 1] - begB;
    const unsigned short* spA = srcids + (size_t)rA * NEDGE + begA;
    const unsigned short* spB = srcids + (size_t)rB * NEDGE + begB;

    const unsigned int* x0u = reinterpret_cast<const unsigned int*>(xb);
    const unsigned int* x1u = x0u + (size_t)N_NODES * 64;

    float aLo = 0.f, aHi = 0.f, bLo = 0.f, bHi = 0.f;

    for (int i = 0; i < dA; i += 4) {
        unsigned int hv[4];
#pragma unroll
        for (int k = 0; k < 4; ++k) {
            int j = i + k;
            int jc = j < dA ? j : dA - 1;
            unsigned int s = spA[jc];
            unsigned int v = x0u[(size_t)s * 64 + lane];
            hv[k] = j < dA ? v : 0u;
        }
#pragma unroll
        for (int k = 0; k < 4; ++k) {
            union { unsigned int u; float f; } lo, hi;
            lo.u = hv[k] << 16;
            hi.u = hv[k] & 0xFFFF0000u;
            aLo += lo.f;
            aHi += hi.f;
        }
    }
    for (int i = 0; i < dB; i += 4) {
        unsigned int hv[4];
#pragma unroll
        for (int k = 0; k < 4; ++k) {
            int j = i + k;
            int jc = j < dB ? j : dB - 1;
            unsigned int s = spB[jc];
            unsigned int v = x1u[(size_t)s * 64 + lane];
            hv[k] = j < dB ? v : 0u;
        }
#pragma unroll
        for (int k = 0; k < 4; ++k) {
            union { unsigned int u; float f; } lo, hi;
            lo.u = hv[k] << 16;
            hi.u = hv[k] & 0xFFFF0000u;
            bLo += lo.f;
            bHi += hi.f;
        }
    }

    float cA0 = wcomp[rA * 2], cA1 = wcomp[rA * 2 + 1];
    float cB0 = wcomp[rB * 2], cB1 = wcomp[rB * 2 + 1];
    float y0l = cA0 * aLo + cB0 * bLo;
    float y0h = cA0 * aHi + cB0 * bHi;
    float y1l = cA1 * aLo + cB1 * bLo;
    float y1h = cA1 * aHi + cB1 * bHi;

    union { __bf16 b[2]; unsigned int u; } p0, p1;
    p0.b[0] = (__bf16)y0l; p0.b[1] = (__bf16)y0h;
    p1.b[0] = (__bf16)y1l; p1.b[1] = (__bf16)y1h;
    unsigned int* yu = reinterpret_cast<unsigned int*>(y);
    yu[(size_t)slot * 128 + lane] = p0.u;        // basis 0 features
    yu[(size_t)slot * 128 + 64 + lane] = p1.u;   // basis 1 features
}

// out[slot] = y[slot][0]*B0 + y[slot][1]*B1 + bias. Operand-swapped MFMA
// (basis W^T as A) -> float4 stores. 64 slots/block, basis frags in LDS.
__global__ __launch_bounds__(256) void gemm_out_kernel(const __bf16* __restrict__ y,
                                                       const __bf16* __restrict__ wfrag,
                                                       const float* __restrict__ bias,
                                                       float* __restrict__ out) {
    __shared__ __bf16 wl[32768];  // 64 KB: both basis frag sets
    {
        const uint4* s = reinterpret_cast<const uint4*>(wfrag);
        uint4* dst = reinterpret_cast<uint4*>(wl);
        int t = threadIdx.x;
#pragma unroll
        for (int i = 0; i < 16; ++i) dst[t + i * 256] = s[t + i * 256];
    }
    __syncthreads();

    const int lane = threadIdx.x & 63;
    const int wave = threadIdx.x >> 6;
    const int g = lane >> 4;
    const int m15 = lane & 15;

    int node = blockIdx.x * 64 + wave * 16 + m15;
    int nodec = node < NSLOT ? node : NSLOT - 1;
    const __bf16* yr = y + (size_t)nodec * 256 + g * 8;

    bf16x8 yfrag[2][4];
#pragma unroll
    for (int b = 0; b < 2; ++b)
#pragma unroll
        for (int kk = 0; kk < 4; ++kk)
            yfrag[b][kk] = *reinterpret_cast<const bf16x8*>(yr + b * 128 + kk * 32);

    const bf16x8* wv = reinterpret_cast<const bf16x8*>(wl);
    bool valid = node < NSLOT;
    float* orow = out + (size_t)node * 128;

#pragma unroll
    for (int n = 0; n < 8; ++n) {
        float4 bv = *reinterpret_cast<const float4*>(bias + n * 16 + g * 4);
        f32x4 acc = (f32x4){bv.x, bv.y, bv.z, bv.w};
#pragma unroll
        for (int b = 0; b < 2; ++b)
#pragma unroll
            for (int kk = 0; kk < 4; ++kk)
                acc = __builtin_amdgcn_mfma_f32_16x16x32_bf16(
                    wv[((b * 8 + n) * 4 + kk) * 64 + lane], yfrag[b][kk], acc, 0, 0, 0);
        if (valid)
            *reinterpret_cast<float4*>(orow + n * 16 + g * 4) =
                (float4){acc[0], acc[1], acc[2], acc[3]};
    }
}

extern "C" void kernel_launch(void* const* d_in, const int* in_sizes, int n_in,
                              void* d_out, int out_size, void* d_ws, size_t ws_size,
                              hipStream_t stream) {
    const float* x0     = (const float*)d_in[0];
    const float* x1     = (const float*)d_in[1];
    const float* weight = (const float*)d_in[2];
    const float* wcomp  = (const float*)d_in[3];
    const float* bias   = (const float*)d_in[4];
    const int* src[4] = {(const int*)d_in[5], (const int*)d_in[7],
                         (const int*)d_in[9], (const int*)d_in[11]};
    const int* dst[4] = {(const int*)d_in[6], (const int*)d_in[8],
                         (const int*)d_in[10], (const int*)d_in[12]};
    float* out = (float*)d_out;

    char* ws = (char*)d_ws;
    __bf16* wfrag = (__bf16*)(ws + OFF_WFRAG);
    __bf16* xb    = (__bf16*)(ws + OFF_XB);
    __bf16* y     = (__bf16*)(ws + OFF_Y);
    int* counts   = (int*)(ws + OFF_CNT);
    int* indptr   = (int*)(ws + OFF_IPTR);
    int* cursor   = (int*)(ws + OFF_CUR);
    int* partials = (int*)(ws + OFF_PART);
    unsigned short* srcids = (unsigned short*)(ws + OFF_SRC);

    wfrag_kernel<<<128, 256, 0, stream>>>(weight, wfrag);
    cast_kernel<<<dim3(3125, 2), 256, 0, stream>>>(x0, x1, xb);

    // ---- per-relation CSR build (uint16 srcids) ----
    hipMemsetAsync(counts, 0, (size_t)4 * CS * 4, stream);
    hist4_kernel<<<(NEDGE + 255) / 256, 256, 0, stream>>>(
        dst[0], dst[1], dst[2], dst[3], counts);
    block_sums_kernel<<<4 * BLKS_PER_REL, 256, 0, stream>>>(counts, partials);
    scan_write_kernel<<<4 * BLKS_PER_REL, 256, 0, stream>>>(counts, partials, indptr, cursor);
    fill4_kernel<<<(NEDGE + 255) / 256, 256, 0, stream>>>(
        src[0], dst[0], src[1], dst[1], src[2], dst[2], src[3], dst[3],
        cursor, srcids);

    // ---- unweighted per-rel gather-sums -> basis-combined y ----
    aggregate_y_kernel<<<NSLOT * 64 / 256, 256, 0, stream>>>(
        xb, indptr, srcids, wcomp, y);

    // ---- dense epilogue: out = y0*B0 + y1*B1 + bias ----
    gemm_out_kernel<<<(NSLOT + 63) / 64, 256, 0, stream>>>(y, wfrag, bias, out);
}